// Round 2
// baseline (370.458 us; speedup 1.0000x reference)
//
#include <hip/hip_runtime.h>
#include <hip/hip_bf16.h>

#define KN  2048   // nodes
#define KD  256    // emb dim = HF
#define KH  4      // heads
#define KF  64     // feat/head
#define KT  64     // time steps

// ---------------- helpers ----------------
__device__ __forceinline__ float wave_sum(float v) {
    #pragma unroll
    for (int o = 32; o > 0; o >>= 1) v += __shfl_xor(v, o, 64);
    return v;
}
__device__ __forceinline__ float wave_max(float v) {
    #pragma unroll
    for (int o = 32; o > 0; o >>= 1) v = fmaxf(v, __shfl_xor(v, o, 64));
    return v;
}

// ---------------- K1: centered+scaled y rows ----------------
// ycs[n,t] = (y[n,t]-mean_n) * rsqrt(sum((y-mean)^2)/(T-1))
__global__ __launch_bounds__(64) void prep_ycs(const float* __restrict__ y,
                                               float* __restrict__ ycs) {
    int n = blockIdx.x, l = threadIdx.x;
    float v = y[n * KT + l];
    float mean = wave_sum(v) * (1.0f / KT);
    float yc = v - mean;
    float ss = wave_sum(yc * yc);
    float rstd = rsqrtf(ss * (1.0f / (KT - 1)));
    ycs[n * KT + l] = yc * rstd;
}

// ---------------- K2: edge classification (0 none, 1 pos, 2 neg) --------
__global__ __launch_bounds__(256) void corr_mask(const float* __restrict__ ycs,
                                                 const float* __restrict__ adj,
                                                 unsigned char* __restrict__ code) {
    __shared__ float Ai[16][KT + 1];
    __shared__ float Bj[16][KT + 1];
    int i0 = blockIdx.y * 16, j0 = blockIdx.x * 16;
    int t = threadIdx.x;
    int r = t >> 4, c4 = (t & 15) * 4;
    {
        const float* pa = &ycs[(i0 + r) * KT + c4];
        const float* pb = &ycs[(j0 + r) * KT + c4];
        #pragma unroll
        for (int u = 0; u < 4; u++) { Ai[r][c4 + u] = pa[u]; Bj[r][c4 + u] = pb[u]; }
    }
    __syncthreads();
    int ty = t >> 4, tx = t & 15;
    float dot = 0.0f;
    #pragma unroll
    for (int k = 0; k < KT; k++) dot += Ai[ty][k] * Bj[tx][k];
    int i = i0 + ty, j = j0 + tx;
    float a = adj[(size_t)i * KN + j];
    unsigned char cc = 0;
    if (a != 0.0f) cc = (dot >= 0.1f) ? (unsigned char)1 : (unsigned char)2;
    code[(size_t)i * KN + j] = cc;
}

// ---------------- K3: GEMM  C[M,Nc] = A[M,K] @ B[K,Nc] (+bias)(+tanh) ----
// all f32 row-major. M%64==0, Nc%64==0, K%16==0.
template <bool TANH>
__global__ __launch_bounds__(256) void gemm256(const float* __restrict__ A,
                                               const float* __restrict__ B,
                                               const float* __restrict__ bias,
                                               float* __restrict__ C,
                                               int M, int Nc, int K) {
    __shared__ float As[16][64];  // [k][m]
    __shared__ float Bs[16][64];  // [k][n]
    int t = threadIdx.x;
    int tx = t & 15, ty = t >> 4;
    int bm = blockIdx.y * 64, bn = blockIdx.x * 64;
    float acc[4][4] = {};
    int ar = t >> 2, ac = (t & 3) * 4;   // A tile loader: 64 rows x 16 k
    int br = t >> 4, bc = (t & 15) * 4;  // B tile loader: 16 k x 64 n
    for (int kt = 0; kt < K; kt += 16) {
        #pragma unroll
        for (int u = 0; u < 4; u++)
            As[ac + u][ar] = A[(size_t)(bm + ar) * K + kt + ac + u];
        #pragma unroll
        for (int u = 0; u < 4; u++)
            Bs[br][bc + u] = B[(size_t)(kt + br) * Nc + bn + bc + u];
        __syncthreads();
        #pragma unroll
        for (int kk = 0; kk < 16; kk++) {
            float4 av = *reinterpret_cast<const float4*>(&As[kk][ty * 4]);
            float4 bv = *reinterpret_cast<const float4*>(&Bs[kk][tx * 4]);
            float a4[4] = {av.x, av.y, av.z, av.w};
            float b4[4] = {bv.x, bv.y, bv.z, bv.w};
            #pragma unroll
            for (int ii = 0; ii < 4; ii++)
                #pragma unroll
                for (int jj = 0; jj < 4; jj++) acc[ii][jj] += a4[ii] * b4[jj];
        }
        __syncthreads();
    }
    #pragma unroll
    for (int ii = 0; ii < 4; ii++) {
        int row = bm + ty * 4 + ii;
        #pragma unroll
        for (int jj = 0; jj < 4; jj++) {
            int col = bn + tx * 4 + jj;
            float v = acc[ii][jj];
            if (bias) v += bias[col];
            if (TANH) v = tanhf(v);
            C[(size_t)row * Nc + col] = v;
        }
    }
}

// ---------------- K4: per-(n,h) attention scores f1,f2 ----------------
__global__ __launch_bounds__(256) void f1f2_kernel(const float* __restrict__ S,
                                                   const float* __restrict__ wu,
                                                   const float* __restrict__ wv,
                                                   float* __restrict__ f1,
                                                   float* __restrict__ f2) {
    int wid = blockIdx.x * 4 + (threadIdx.x >> 6);
    int lane = threadIdx.x & 63;
    int n = wid >> 2, h = wid & 3;
    float v = S[(size_t)n * KD + h * KF + lane];
    float u = wu[h * KF + lane];
    float w = wv[h * KF + lane];
    float s1 = wave_sum(v * u);
    float s2 = wave_sum(v * w);
    if (lane == 0) { f1[h * KN + n] = s1; f2[h * KN + n] = s2; }
}

// ---------------- K5: sparse masked-softmax GAT row ----------------
// one wave per (i,h): compact edge list, softmax, aggregate s, fused epilogue
#define MAXE 256
__global__ __launch_bounds__(64) void attn_kernel(const unsigned char* __restrict__ code,
                                                  int want,
                                                  const float* __restrict__ f1,
                                                  const float* __restrict__ f2,
                                                  const float* __restrict__ S,
                                                  const float* __restrict__ P,
                                                  const float* __restrict__ b,
                                                  float* __restrict__ G) {
    __shared__ int jl[MAXE];
    __shared__ float wl[MAXE];
    int bid = blockIdx.x;
    int i = bid >> 2, h = bid & 3;
    int lane = threadIdx.x;
    float f2i = f2[h * KN + i];
    int count = 0;
    for (int base = 0; base < KN; base += 64) {
        int j = base + lane;
        bool p = (code[(size_t)i * KN + j] == (unsigned char)want);
        unsigned long long bal = __ballot(p);
        int pre = __popcll(bal & ((1ull << lane) - 1ull));
        if (p) {
            float x = f1[h * KN + j] + f2i;
            float lg = (x > 0.0f) ? x : 0.2f * x;   // leaky_relu 0.2
            int idx = count + pre;
            if (idx < MAXE) { jl[idx] = j; wl[idx] = lg; }
        }
        count += (int)__popcll(bal);
    }
    if (count > MAXE) count = MAXE;  // statistically unreachable; prevents OOB
    __syncthreads();
    float m = -1e30f;
    for (int k = lane; k < count; k += 64) m = fmaxf(m, wl[k]);
    m = wave_max(m);
    float ps = 0.0f;
    for (int k = lane; k < count; k += 64) {
        float e = __expf(wl[k] - m);
        wl[k] = e;
        ps += e;
    }
    float denom = wave_sum(ps);
    __syncthreads();
    float acc = 0.0f;
    for (int k = 0; k < count; k++) {
        float w = wl[k];
        int j = jl[k];
        acc += w * S[(size_t)j * KD + h * KF + lane];
    }
    float out = (count > 0) ? acc * (1.0f / denom) : 0.0f;
    int col = h * KF + lane;
    G[(size_t)i * KD + col] = out + b[col] + P[(size_t)i * KD + col];
}

// ---------------- K8: semantic attention blend + colsum partials --------
__global__ __launch_bounds__(256) void combine_kernel(const float* __restrict__ T0,
                                                      const float* __restrict__ T1,
                                                      const float* __restrict__ T2,
                                                      const float* __restrict__ w2,
                                                      const float* __restrict__ sup,
                                                      const float* __restrict__ psup,
                                                      const float* __restrict__ nsup,
                                                      float* __restrict__ X,
                                                      float* __restrict__ colsum) {
    int n = blockIdx.x, d = threadIdx.x;
    size_t idx = (size_t)n * KD + d;
    float w2d = w2[d];
    float p0 = T0[idx] * w2d, p1 = T1[idx] * w2d, p2 = T2[idx] * w2d;
    __shared__ float sbuf[4][3];
    int wv = d >> 6, lane = d & 63;
    float s0 = wave_sum(p0), s1 = wave_sum(p1), s2 = wave_sum(p2);
    if (lane == 0) { sbuf[wv][0] = s0; sbuf[wv][1] = s1; sbuf[wv][2] = s2; }
    __syncthreads();
    float w0 = sbuf[0][0] + sbuf[1][0] + sbuf[2][0] + sbuf[3][0];
    float w1 = sbuf[0][1] + sbuf[1][1] + sbuf[2][1] + sbuf[3][1];
    float w2l = sbuf[0][2] + sbuf[1][2] + sbuf[2][2] + sbuf[3][2];
    float mm = fmaxf(w0, fmaxf(w1, w2l));
    float e0 = __expf(w0 - mm), e1 = __expf(w1 - mm), e2 = __expf(w2l - mm);
    float inv = 1.0f / (e0 + e1 + e2);
    float x = (e0 * inv) * sup[idx] + (e1 * inv) * psup[idx] + (e2 * inv) * nsup[idx];
    X[idx] = x;
    atomicAdd(&colsum[(n & 7) * KD + d], x);
}

// ---------------- K9: PairNorm PN-SI + store ----------------
__global__ __launch_bounds__(256) void final_kernel(const float* __restrict__ X,
                                                    const float* __restrict__ colsum,
                                                    float* __restrict__ out) {
    int n = blockIdx.x, d = threadIdx.x;
    float cs = 0.0f;
    #pragma unroll
    for (int r = 0; r < 8; r++) cs += colsum[r * KD + d];
    float mean = cs * (1.0f / KN);
    float xc = X[(size_t)n * KD + d] - mean;
    __shared__ float sbuf[4];
    int wv = d >> 6, lane = d & 63;
    float s = wave_sum(xc * xc);
    if (lane == 0) sbuf[wv] = s;
    __syncthreads();
    float ss = sbuf[0] + sbuf[1] + sbuf[2] + sbuf[3];
    out[(size_t)n * KD + d] = xc * rsqrtf(1e-6f + ss);
}

// ---------------- host ----------------
extern "C" void kernel_launch(void* const* d_in, const int* in_sizes, int n_in,
                              void* d_out, int out_size, void* d_ws, size_t ws_size,
                              hipStream_t stream) {
    typedef const float* fp;
    fp emb    = (fp)d_in[0];
    fp y_as_x = (fp)d_in[1];
    fp adj    = (fp)d_in[2];
    fp pos_w  = (fp)d_in[3],  pos_wu = (fp)d_in[4],  pos_wv = (fp)d_in[5];
    fp pos_b  = (fp)d_in[6],  pos_pw = (fp)d_in[7],  pos_pb = (fp)d_in[8];
    fp neg_w  = (fp)d_in[9],  neg_wu = (fp)d_in[10], neg_wv = (fp)d_in[11];
    fp neg_b  = (fp)d_in[12], neg_pw = (fp)d_in[13], neg_pb = (fp)d_in[14];
    fp self_w = (fp)d_in[15], self_b = (fp)d_in[16];
    fp mlp_pos_w = (fp)d_in[17], mlp_pos_b = (fp)d_in[18];
    fp mlp_neg_w = (fp)d_in[19], mlp_neg_b = (fp)d_in[20];
    fp sem_w1 = (fp)d_in[21], sem_b1 = (fp)d_in[22], sem_w2 = (fp)d_in[23];
    float* out = (float*)d_out;

    char* ws = (char*)d_ws;
    // region A (512 KB): ycs, dead after corr_mask; then reused for f1/f2/colsum
    float* ycs        = (float*)(ws + 0x0000000);
    float* f1p        = (float*)(ws + 0x0000000);
    float* f2p        = (float*)(ws + 0x0008000);
    float* f1n        = (float*)(ws + 0x0010000);
    float* f2n        = (float*)(ws + 0x0018000);
    float* colsum     = (float*)(ws + 0x0020000);
    unsigned char* cd = (unsigned char*)(ws + 0x0080000);  // 4 MB
    float* S_pos      = (float*)(ws + 0x0480000);          // 2 MB each
    float* S_neg      = (float*)(ws + 0x0680000);
    float* P_pos      = (float*)(ws + 0x0880000);          // later T0
    float* P_neg      = (float*)(ws + 0x0A80000);          // later T1
    float* G_pos      = (float*)(ws + 0x0C80000);          // later T2
    float* G_neg      = (float*)(ws + 0x0E80000);          // later X
    float* sup        = (float*)(ws + 0x1080000);
    float* psup       = (float*)(ws + 0x1280000);
    float* nsup       = (float*)(ws + 0x1480000);
    float* T0 = P_pos, *T1 = P_neg, *T2 = G_pos, *X = G_neg;

    dim3 gGemm(KD / 64, KN / 64);  // (4, 32)

    prep_ycs<<<KN, 64, 0, stream>>>(y_as_x, ycs);
    corr_mask<<<dim3(KN / 16, KN / 16), 256, 0, stream>>>(ycs, adj, cd);

    gemm256<false><<<gGemm, 256, 0, stream>>>(emb, pos_w, nullptr, S_pos, KN, KD, KD);
    gemm256<false><<<gGemm, 256, 0, stream>>>(emb, neg_w, nullptr, S_neg, KN, KD, KD);
    gemm256<false><<<gGemm, 256, 0, stream>>>(emb, pos_pw, pos_pb, P_pos, KN, KD, KD);
    gemm256<false><<<gGemm, 256, 0, stream>>>(emb, neg_pw, neg_pb, P_neg, KN, KD, KD);
    gemm256<false><<<gGemm, 256, 0, stream>>>(emb, self_w, self_b, sup, KN, KD, KD);

    f1f2_kernel<<<KN, 256, 0, stream>>>(S_pos, pos_wu, pos_wv, f1p, f2p);
    f1f2_kernel<<<KN, 256, 0, stream>>>(S_neg, neg_wu, neg_wv, f1n, f2n);

    attn_kernel<<<KN * KH, 64, 0, stream>>>(cd, 1, f1p, f2p, S_pos, P_pos, pos_b, G_pos);
    attn_kernel<<<KN * KH, 64, 0, stream>>>(cd, 2, f1n, f2n, S_neg, P_neg, neg_b, G_neg);

    gemm256<false><<<gGemm, 256, 0, stream>>>(G_pos, mlp_pos_w, mlp_pos_b, psup, KN, KD, KD);
    gemm256<false><<<gGemm, 256, 0, stream>>>(G_neg, mlp_neg_w, mlp_neg_b, nsup, KN, KD, KD);

    gemm256<true><<<gGemm, 256, 0, stream>>>(sup,  sem_w1, sem_b1, T0, KN, KD, KD);
    gemm256<true><<<gGemm, 256, 0, stream>>>(psup, sem_w1, sem_b1, T1, KN, KD, KD);
    gemm256<true><<<gGemm, 256, 0, stream>>>(nsup, sem_w1, sem_b1, T2, KN, KD, KD);

    hipMemsetAsync(colsum, 0, 8 * KD * sizeof(float), stream);
    combine_kernel<<<KN, 256, 0, stream>>>(T0, T1, T2, sem_w2, sup, psup, nsup, X, colsum);
    final_kernel<<<KN, 256, 0, stream>>>(X, colsum, out);
}

// Round 3
// 230.949 us; speedup vs baseline: 1.6041x; 1.6041x over previous
//
#include <hip/hip_runtime.h>
#include <hip/hip_bf16.h>

#define KN  2048   // nodes
#define KD  256    // emb dim = HF
#define KH  4      // heads
#define KF  64     // feat/head
#define KT  64     // time steps

// ---------------- helpers ----------------
__device__ __forceinline__ float wave_sum(float v) {
    #pragma unroll
    for (int o = 32; o > 0; o >>= 1) v += __shfl_xor(v, o, 64);
    return v;
}
__device__ __forceinline__ float wave_max(float v) {
    #pragma unroll
    for (int o = 32; o > 0; o >>= 1) v = fmaxf(v, __shfl_xor(v, o, 64));
    return v;
}

// ---------------- K0: pack 5 emb-side weight matrices into one 256x1280 ----
__global__ __launch_bounds__(256) void pack_w(const float* __restrict__ pw,
                                              const float* __restrict__ nw,
                                              const float* __restrict__ ppw,
                                              const float* __restrict__ npw,
                                              const float* __restrict__ sw,
                                              const float* __restrict__ ppb,
                                              const float* __restrict__ npb,
                                              const float* __restrict__ sb,
                                              float* __restrict__ Wbig,
                                              float* __restrict__ biasbig) {
    int k = blockIdx.x;
    for (int j = threadIdx.x; j < 1280; j += 256) {
        int sel = j >> 8, jj = j & 255;
        const float* src = (sel == 0) ? pw : (sel == 1) ? nw : (sel == 2) ? ppw
                          : (sel == 3) ? npw : sw;
        Wbig[k * 1280 + j] = src[k * 256 + jj];
    }
    if (blockIdx.x == 0) {
        for (int j = threadIdx.x; j < 1280; j += 256) {
            int sel = j >> 8, jj = j & 255;
            float b = 0.0f;
            if (sel == 2) b = ppb[jj];
            else if (sel == 3) b = npb[jj];
            else if (sel == 4) b = sb[jj];
            biasbig[j] = b;
        }
    }
}

// ---------------- K1: centered+scaled y rows ----------------
__global__ __launch_bounds__(64) void prep_ycs(const float* __restrict__ y,
                                               float* __restrict__ ycs) {
    int n = blockIdx.x, l = threadIdx.x;
    float v = y[n * KT + l];
    float mean = wave_sum(v) * (1.0f / KT);
    float yc = v - mean;
    float ss = wave_sum(yc * yc);
    float rstd = rsqrtf(ss * (1.0f / (KT - 1)));
    ycs[n * KT + l] = yc * rstd;
}

// ---------------- K2: edge classification, 64x64 tile, 4x4/thread --------
__global__ __launch_bounds__(256) void corr_mask(const float* __restrict__ ycs,
                                                 const float* __restrict__ adj,
                                                 unsigned char* __restrict__ code) {
    __shared__ float As[16][68];  // [k][i]
    __shared__ float Bs[16][68];  // [k][j]
    int t = threadIdx.x;
    int tx = t & 15, ty = t >> 4;
    int i0 = blockIdx.y * 64, j0 = blockIdx.x * 64;
    int ar = t >> 2, ac = (t & 3) * 4;
    float acc[4][4] = {};
    for (int kt = 0; kt < KT; kt += 16) {
        float4 a4 = *reinterpret_cast<const float4*>(&ycs[(size_t)(i0 + ar) * KT + kt + ac]);
        float4 b4 = *reinterpret_cast<const float4*>(&ycs[(size_t)(j0 + ar) * KT + kt + ac]);
        As[ac + 0][ar] = a4.x; As[ac + 1][ar] = a4.y; As[ac + 2][ar] = a4.z; As[ac + 3][ar] = a4.w;
        Bs[ac + 0][ar] = b4.x; Bs[ac + 1][ar] = b4.y; Bs[ac + 2][ar] = b4.z; Bs[ac + 3][ar] = b4.w;
        __syncthreads();
        #pragma unroll
        for (int kk = 0; kk < 16; kk++) {
            float4 av = *reinterpret_cast<const float4*>(&As[kk][ty * 4]);
            float4 bv = *reinterpret_cast<const float4*>(&Bs[kk][tx * 4]);
            float a4v[4] = {av.x, av.y, av.z, av.w};
            float b4v[4] = {bv.x, bv.y, bv.z, bv.w};
            #pragma unroll
            for (int ii = 0; ii < 4; ii++)
                #pragma unroll
                for (int jj = 0; jj < 4; jj++) acc[ii][jj] += a4v[ii] * b4v[jj];
        }
        __syncthreads();
    }
    #pragma unroll
    for (int ii = 0; ii < 4; ii++) {
        int i = i0 + ty * 4 + ii;
        int jb = j0 + tx * 4;
        float4 av = *reinterpret_cast<const float4*>(&adj[(size_t)i * KN + jb]);
        float a4v[4] = {av.x, av.y, av.z, av.w};
        uchar4 cc;
        unsigned char* c = (unsigned char*)&cc;
        #pragma unroll
        for (int jj = 0; jj < 4; jj++)
            c[jj] = (a4v[jj] != 0.0f) ? ((acc[ii][jj] >= 0.1f) ? 1 : 2) : 0;
        *reinterpret_cast<uchar4*>(&code[(size_t)i * KN + jb]) = cc;
    }
}

// ---------------- shared GEMM tile body: 64x64, K=256, 4x4/thread --------
template <bool TANH>
__device__ __forceinline__ void gemm_body(const float* __restrict__ A, int lda, int bm,
                                          const float* __restrict__ B, int ldb, int bn,
                                          const float* __restrict__ bias, int bcol,
                                          float* __restrict__ C, int ldc, int cn) {
    __shared__ float As[16][68];  // [k][m]
    __shared__ float Bs[16][68];  // [k][n]
    int t = threadIdx.x;
    int tx = t & 15, ty = t >> 4;
    int ar = t >> 2, ac = (t & 3) * 4;       // A loader: row, k-quad
    int bc = t & 63, br = (t >> 6) * 4;      // B loader: col, k-quad (wave-uniform br)
    float acc[4][4] = {};
    for (int kt = 0; kt < KD; kt += 16) {
        float4 a4 = *reinterpret_cast<const float4*>(&A[(size_t)(bm + ar) * lda + kt + ac]);
        float b4[4];
        #pragma unroll
        for (int u = 0; u < 4; u++) b4[u] = B[(size_t)(kt + br + u) * ldb + bn + bc];
        As[ac + 0][ar] = a4.x; As[ac + 1][ar] = a4.y; As[ac + 2][ar] = a4.z; As[ac + 3][ar] = a4.w;
        #pragma unroll
        for (int u = 0; u < 4; u++) Bs[br + u][bc] = b4[u];
        __syncthreads();
        #pragma unroll
        for (int kk = 0; kk < 16; kk++) {
            float4 av = *reinterpret_cast<const float4*>(&As[kk][ty * 4]);
            float4 bv = *reinterpret_cast<const float4*>(&Bs[kk][tx * 4]);
            float a4v[4] = {av.x, av.y, av.z, av.w};
            float b4v[4] = {bv.x, bv.y, bv.z, bv.w};
            #pragma unroll
            for (int ii = 0; ii < 4; ii++)
                #pragma unroll
                for (int jj = 0; jj < 4; jj++) acc[ii][jj] += a4v[ii] * b4v[jj];
        }
        __syncthreads();
    }
    #pragma unroll
    for (int ii = 0; ii < 4; ii++) {
        int row = bm + ty * 4 + ii;
        #pragma unroll
        for (int jj = 0; jj < 4; jj++) {
            int col = tx * 4 + jj;
            float v = acc[ii][jj] + bias[bcol + col];
            if (TANH) v = tanhf(v);
            C[(size_t)row * ldc + cn + col] = v;
        }
    }
}

// K3a: emb @ Wbig(256x1280) -> 5 destination buffers
struct Ptr5 { float* c0; float* c1; float* c2; float* c3; float* c4; };
__global__ __launch_bounds__(256) void gemm_emb(const float* __restrict__ A,
                                                const float* __restrict__ Bbig,
                                                const float* __restrict__ biasbig,
                                                Ptr5 cp) {
    int tn = blockIdx.x;            // 0..19
    int bn = tn * 64;               // packed col
    int buf = bn >> 8;              // which dest
    int coloff = bn & 255;
    float* C = (buf == 0) ? cp.c0 : (buf == 1) ? cp.c1 : (buf == 2) ? cp.c2
             : (buf == 3) ? cp.c3 : cp.c4;
    gemm_body<false>(A, KD, blockIdx.y * 64, Bbig, 1280, bn, biasbig, bn, C, KD, coloff);
}

// K3b: [G_pos;G_neg](4096x256) @ {mlp_pos_w|mlp_neg_w} -> [psup;nsup]
__global__ __launch_bounds__(256) void gemm_mlp(const float* __restrict__ Astack,
                                                const float* __restrict__ B0,
                                                const float* __restrict__ B1,
                                                const float* __restrict__ b0,
                                                const float* __restrict__ b1,
                                                float* __restrict__ Cstack) {
    int bm = blockIdx.y * 64;
    bool sel = bm >= KN;
    gemm_body<false>(Astack, KD, bm, sel ? B1 : B0, KD, blockIdx.x * 64,
                     sel ? b1 : b0, blockIdx.x * 64, Cstack, KD, blockIdx.x * 64);
}

// K3c: [sup;psup;nsup](6144x256) @ sem_w1 + b, tanh -> [T0;T1;T2]
__global__ __launch_bounds__(256) void gemm_sem(const float* __restrict__ Astack,
                                                const float* __restrict__ B,
                                                const float* __restrict__ bias,
                                                float* __restrict__ Cstack) {
    gemm_body<true>(Astack, KD, blockIdx.y * 64, B, KD, blockIdx.x * 64,
                    bias, blockIdx.x * 64, Cstack, KD, blockIdx.x * 64);
}

// ---------------- K4: per-(n,h) attention scores f1,f2 (pos+neg fused) ----
__global__ __launch_bounds__(256) void f1f2_kernel(const float* __restrict__ Sp,
                                                   const float* __restrict__ Sn,
                                                   const float* __restrict__ wup,
                                                   const float* __restrict__ wvp,
                                                   const float* __restrict__ wun,
                                                   const float* __restrict__ wvn,
                                                   float* __restrict__ f1p,
                                                   float* __restrict__ f2p,
                                                   float* __restrict__ f1n,
                                                   float* __restrict__ f2n) {
    int b = blockIdx.x;
    int rel = b >> 11;               // 0 pos, 1 neg
    int n = b & (KN - 1);
    int h = threadIdx.x >> 6, lane = threadIdx.x & 63;
    const float* S = rel ? Sn : Sp;
    const float* wu = rel ? wun : wup;
    const float* wv = rel ? wvn : wvp;
    float* f1 = rel ? f1n : f1p;
    float* f2 = rel ? f2n : f2p;
    float v = S[(size_t)n * KD + h * KF + lane];
    float s1 = wave_sum(v * wu[h * KF + lane]);
    float s2 = wave_sum(v * wv[h * KF + lane]);
    if (lane == 0) { f1[h * KN + n] = s1; f2[h * KN + n] = s2; }
}

// ---------------- K5: sparse masked-softmax GAT row (pos+neg fused) ------
#define MAXE 256
__global__ __launch_bounds__(64) void attn_kernel(const unsigned char* __restrict__ code,
                                                  const float* __restrict__ f1p,
                                                  const float* __restrict__ f2p,
                                                  const float* __restrict__ Sp,
                                                  const float* __restrict__ Pp,
                                                  const float* __restrict__ bp,
                                                  float* __restrict__ Gp,
                                                  const float* __restrict__ f1n,
                                                  const float* __restrict__ f2n,
                                                  const float* __restrict__ Sn,
                                                  const float* __restrict__ Pn,
                                                  const float* __restrict__ bn,
                                                  float* __restrict__ Gn) {
    __shared__ int jl[MAXE];
    __shared__ float wl[MAXE];
    int bid = blockIdx.x;
    int rel = bid >> 13;                     // 0 pos, 1 neg
    int i = (bid & 8191) >> 2, h = bid & 3;
    unsigned char want = rel ? 2 : 1;
    const float* f1 = rel ? f1n : f1p;
    const float* f2 = rel ? f2n : f2p;
    const float* S  = rel ? Sn : Sp;
    const float* P  = rel ? Pn : Pp;
    const float* b  = rel ? bn : bp;
    float* G        = rel ? Gn : Gp;
    int lane = threadIdx.x;
    float f2i = f2[h * KN + i];
    int count = 0;
    for (int base = 0; base < KN; base += 256) {
        uchar4 cv = *reinterpret_cast<const uchar4*>(&code[(size_t)i * KN + base + lane * 4]);
        const unsigned char* ce = (const unsigned char*)&cv;
        #pragma unroll
        for (int e = 0; e < 4; e++) {
            bool p = (ce[e] == want);
            unsigned long long bal = __ballot(p);
            int pre = __popcll(bal & ((1ull << lane) - 1ull));
            if (p) {
                int j = base + lane * 4 + e;
                float x = f1[h * KN + j] + f2i;
                float lg = (x > 0.0f) ? x : 0.2f * x;   // leaky_relu 0.2
                int idx = count + pre;
                if (idx < MAXE) { jl[idx] = j; wl[idx] = lg; }
            }
            count += (int)__popcll(bal);
        }
    }
    if (count > MAXE) count = MAXE;
    __syncthreads();
    float m = -1e30f;
    for (int k = lane; k < count; k += 64) m = fmaxf(m, wl[k]);
    m = wave_max(m);
    float ps = 0.0f;
    for (int k = lane; k < count; k += 64) {
        float e = __expf(wl[k] - m);
        wl[k] = e;
        ps += e;
    }
    float denom = wave_sum(ps);
    __syncthreads();
    float acc = 0.0f;
    for (int k = 0; k < count; k++) {
        acc += wl[k] * S[(size_t)jl[k] * KD + h * KF + lane];
    }
    float out = (count > 0) ? acc * (1.0f / denom) : 0.0f;
    int col = h * KF + lane;
    G[(size_t)i * KD + col] = out + b[col] + P[(size_t)i * KD + col];
}

// ---------------- K8: semantic attention blend + colsum partials --------
__global__ __launch_bounds__(256) void combine_kernel(const float* __restrict__ T0,
                                                      const float* __restrict__ T1,
                                                      const float* __restrict__ T2,
                                                      const float* __restrict__ w2,
                                                      const float* __restrict__ sup,
                                                      const float* __restrict__ psup,
                                                      const float* __restrict__ nsup,
                                                      float* __restrict__ X,
                                                      float* __restrict__ colsum) {
    int n = blockIdx.x, d = threadIdx.x;
    size_t idx = (size_t)n * KD + d;
    float w2d = w2[d];
    float p0 = T0[idx] * w2d, p1 = T1[idx] * w2d, p2 = T2[idx] * w2d;
    __shared__ float sbuf[4][3];
    int wv = d >> 6, lane = d & 63;
    float s0 = wave_sum(p0), s1 = wave_sum(p1), s2 = wave_sum(p2);
    if (lane == 0) { sbuf[wv][0] = s0; sbuf[wv][1] = s1; sbuf[wv][2] = s2; }
    __syncthreads();
    float w0 = sbuf[0][0] + sbuf[1][0] + sbuf[2][0] + sbuf[3][0];
    float w1 = sbuf[0][1] + sbuf[1][1] + sbuf[2][1] + sbuf[3][1];
    float w2l = sbuf[0][2] + sbuf[1][2] + sbuf[2][2] + sbuf[3][2];
    float mm = fmaxf(w0, fmaxf(w1, w2l));
    float e0 = __expf(w0 - mm), e1 = __expf(w1 - mm), e2 = __expf(w2l - mm);
    float inv = 1.0f / (e0 + e1 + e2);
    float x = (e0 * inv) * sup[idx] + (e1 * inv) * psup[idx] + (e2 * inv) * nsup[idx];
    X[idx] = x;
    atomicAdd(&colsum[(n & 7) * KD + d], x);
}

// ---------------- K9: PairNorm PN-SI + store ----------------
__global__ __launch_bounds__(256) void final_kernel(const float* __restrict__ X,
                                                    const float* __restrict__ colsum,
                                                    float* __restrict__ out) {
    int n = blockIdx.x, d = threadIdx.x;
    float cs = 0.0f;
    #pragma unroll
    for (int r = 0; r < 8; r++) cs += colsum[r * KD + d];
    float mean = cs * (1.0f / KN);
    float xc = X[(size_t)n * KD + d] - mean;
    __shared__ float sbuf[4];
    int wv = d >> 6, lane = d & 63;
    float s = wave_sum(xc * xc);
    if (lane == 0) sbuf[wv] = s;
    __syncthreads();
    float ss = sbuf[0] + sbuf[1] + sbuf[2] + sbuf[3];
    out[(size_t)n * KD + d] = xc * rsqrtf(1e-6f + ss);
}

// ---------------- host ----------------
extern "C" void kernel_launch(void* const* d_in, const int* in_sizes, int n_in,
                              void* d_out, int out_size, void* d_ws, size_t ws_size,
                              hipStream_t stream) {
    typedef const float* fp;
    fp emb    = (fp)d_in[0];
    fp y_as_x = (fp)d_in[1];
    fp adj    = (fp)d_in[2];
    fp pos_w  = (fp)d_in[3],  pos_wu = (fp)d_in[4],  pos_wv = (fp)d_in[5];
    fp pos_b  = (fp)d_in[6],  pos_pw = (fp)d_in[7],  pos_pb = (fp)d_in[8];
    fp neg_w  = (fp)d_in[9],  neg_wu = (fp)d_in[10], neg_wv = (fp)d_in[11];
    fp neg_b  = (fp)d_in[12], neg_pw = (fp)d_in[13], neg_pb = (fp)d_in[14];
    fp self_w = (fp)d_in[15], self_b = (fp)d_in[16];
    fp mlp_pos_w = (fp)d_in[17], mlp_pos_b = (fp)d_in[18];
    fp mlp_neg_w = (fp)d_in[19], mlp_neg_b = (fp)d_in[20];
    fp sem_w1 = (fp)d_in[21], sem_b1 = (fp)d_in[22], sem_w2 = (fp)d_in[23];
    float* out = (float*)d_out;

    char* ws = (char*)d_ws;
    // region A: ycs (512K), reused for f1/f2/colsum after corr_mask
    float* ycs        = (float*)(ws + 0x0000000);
    float* f1p        = (float*)(ws + 0x0000000);
    float* f2p        = (float*)(ws + 0x0008000);
    float* f1n        = (float*)(ws + 0x0010000);
    float* f2n        = (float*)(ws + 0x0018000);
    float* colsum     = (float*)(ws + 0x0020000);
    unsigned char* cd = (unsigned char*)(ws + 0x0080000);  // 4 MB
    float* S_pos      = (float*)(ws + 0x0480000);          // 2 MB each
    float* S_neg      = (float*)(ws + 0x0680000);
    float* P_pos      = (float*)(ws + 0x0880000);          // later T0
    float* P_neg      = (float*)(ws + 0x0A80000);          // later T1
    float* G_pos      = (float*)(ws + 0x0C80000);          // later T2  (G_pos|G_neg contiguous)
    float* G_neg      = (float*)(ws + 0x0E80000);          // later X
    float* sup        = (float*)(ws + 0x1080000);          // sup|psup|nsup contiguous
    float* psup       = (float*)(ws + 0x1280000);          // psup|nsup contiguous (mlp C)
    float* nsup       = (float*)(ws + 0x1480000);          // also hosts Wbig BEFORE mlp runs
    float* Wbig       = (float*)(ws + 0x1480000);          // 1.25 MB, dead before nsup written
    float* biasbig    = (float*)(ws + 0x1480000 + 0x140000);
    float* T0 = P_pos, *T1 = P_neg, *T2 = G_pos, *X = G_neg;

    pack_w<<<256, 256, 0, stream>>>(pos_w, neg_w, pos_pw, neg_pw, self_w,
                                    pos_pb, neg_pb, self_b, Wbig, biasbig);
    prep_ycs<<<KN, 64, 0, stream>>>(y_as_x, ycs);
    corr_mask<<<dim3(KN / 64, KN / 64), 256, 0, stream>>>(ycs, adj, cd);

    Ptr5 cp = {S_pos, S_neg, P_pos, P_neg, sup};
    gemm_emb<<<dim3(20, KN / 64), 256, 0, stream>>>(emb, Wbig, biasbig, cp);

    f1f2_kernel<<<2 * KN, 256, 0, stream>>>(S_pos, S_neg, pos_wu, pos_wv, neg_wu, neg_wv,
                                            f1p, f2p, f1n, f2n);

    attn_kernel<<<2 * KN * KH, 64, 0, stream>>>(cd,
                                                f1p, f2p, S_pos, P_pos, pos_b, G_pos,
                                                f1n, f2n, S_neg, P_neg, neg_b, G_neg);

    gemm_mlp<<<dim3(4, 2 * KN / 64), 256, 0, stream>>>(G_pos, mlp_pos_w, mlp_neg_w,
                                                       mlp_pos_b, mlp_neg_b, psup);
    gemm_sem<<<dim3(4, 3 * KN / 64), 256, 0, stream>>>(sup, sem_w1, sem_b1, T0);

    hipMemsetAsync(colsum, 0, 8 * KD * sizeof(float), stream);
    combine_kernel<<<KN, 256, 0, stream>>>(T0, T1, T2, sem_w2, sup, psup, nsup, X, colsum);
    final_kernel<<<KN, 256, 0, stream>>>(X, colsum, out);
}

// Round 4
// 173.330 us; speedup vs baseline: 2.1373x; 1.3324x over previous
//
#include <hip/hip_runtime.h>
#include <hip/hip_bf16.h>

#define KN  2048   // nodes
#define KD  256    // emb dim = HF
#define KH  4      // heads
#define KF  64     // feat/head
#define KT  64     // time steps

typedef __attribute__((ext_vector_type(8))) short short8;
typedef __attribute__((ext_vector_type(4))) float floatx4;

// ---------------- helpers ----------------
__device__ __forceinline__ float wave_sum(float v) {
    #pragma unroll
    for (int o = 32; o > 0; o >>= 1) v += __shfl_xor(v, o, 64);
    return v;
}
__device__ __forceinline__ float wave_max(float v) {
    #pragma unroll
    for (int o = 32; o > 0; o >>= 1) v = fmaxf(v, __shfl_xor(v, o, 64));
    return v;
}
__device__ __forceinline__ short f2bs(float x) {
    union { __hip_bfloat16 h; short s; } u;
    u.h = __float2bfloat16(x);
    return u.s;
}

// ---------------- K0: setup (pack Wbig + ycs + zero colsum) ----------------
__global__ __launch_bounds__(256) void setup_kernel(
    const float* __restrict__ y, float* __restrict__ ycs,
    const float* __restrict__ pw, const float* __restrict__ nw,
    const float* __restrict__ ppw, const float* __restrict__ npw,
    const float* __restrict__ sw,
    const float* __restrict__ ppb, const float* __restrict__ npb,
    const float* __restrict__ sb,
    float* __restrict__ Wbig, float* __restrict__ biasbig,
    float* __restrict__ colsum)
{
    int blk = blockIdx.x;
    if (blk < 512) {
        int w = threadIdx.x >> 6, lane = threadIdx.x & 63;
        int n = blk * 4 + w;
        float v = y[n * KT + lane];
        float mean = wave_sum(v) * (1.0f / KT);
        float yc = v - mean;
        float ss = wave_sum(yc * yc);
        ycs[n * KT + lane] = yc * rsqrtf(ss * (1.0f / (KT - 1)));
    } else {
        int k = blk - 512;   // 0..255
        for (int j = threadIdx.x; j < 1280; j += 256) {
            int sel = j >> 8, jj = j & 255;
            const float* src = (sel == 0) ? pw : (sel == 1) ? nw : (sel == 2) ? ppw
                              : (sel == 3) ? npw : sw;
            Wbig[k * 1280 + j] = src[k * 256 + jj];
        }
        if (k == 0) {
            for (int j = threadIdx.x; j < 1280; j += 256) {
                int sel = j >> 8, jj = j & 255;
                biasbig[j] = (sel == 2) ? ppb[jj] : (sel == 3) ? npb[jj]
                           : (sel == 4) ? sb[jj] : 0.0f;
            }
        }
        if (k == 1) {
            for (int j = threadIdx.x; j < 8 * KD; j += 256) colsum[j] = 0.0f;
        }
    }
}

// ---------------- corr body: 64x64 tile, 4x4/thread, f32 ----------------
__device__ __forceinline__ void corr_body(const float* __restrict__ ycs,
                                          const float* __restrict__ adj,
                                          unsigned char* __restrict__ code,
                                          int blk, char* smem) {
    float (*As)[68] = (float(*)[68])smem;            // 16x68 f32 = 4352 B
    float (*Bs)[68] = (float(*)[68])(smem + 4352);
    int t = threadIdx.x;
    int tx = t & 15, ty = t >> 4;
    int j0 = (blk & 31) * 64, i0 = (blk >> 5) * 64;
    int ar = t >> 2, ac = (t & 3) * 4;
    float acc[4][4] = {};
    for (int kt = 0; kt < KT; kt += 16) {
        float4 a4 = *reinterpret_cast<const float4*>(&ycs[(size_t)(i0 + ar) * KT + kt + ac]);
        float4 b4 = *reinterpret_cast<const float4*>(&ycs[(size_t)(j0 + ar) * KT + kt + ac]);
        As[ac + 0][ar] = a4.x; As[ac + 1][ar] = a4.y; As[ac + 2][ar] = a4.z; As[ac + 3][ar] = a4.w;
        Bs[ac + 0][ar] = b4.x; Bs[ac + 1][ar] = b4.y; Bs[ac + 2][ar] = b4.z; Bs[ac + 3][ar] = b4.w;
        __syncthreads();
        #pragma unroll
        for (int kk = 0; kk < 16; kk++) {
            float4 av = *reinterpret_cast<const float4*>(&As[kk][ty * 4]);
            float4 bv = *reinterpret_cast<const float4*>(&Bs[kk][tx * 4]);
            float a4v[4] = {av.x, av.y, av.z, av.w};
            float b4v[4] = {bv.x, bv.y, bv.z, bv.w};
            #pragma unroll
            for (int ii = 0; ii < 4; ii++)
                #pragma unroll
                for (int jj = 0; jj < 4; jj++) acc[ii][jj] += a4v[ii] * b4v[jj];
        }
        __syncthreads();
    }
    #pragma unroll
    for (int ii = 0; ii < 4; ii++) {
        int i = i0 + ty * 4 + ii;
        int jb = j0 + tx * 4;
        float4 av = *reinterpret_cast<const float4*>(&adj[(size_t)i * KN + jb]);
        float a4v[4] = {av.x, av.y, av.z, av.w};
        uchar4 cc;
        unsigned char* c = (unsigned char*)&cc;
        #pragma unroll
        for (int jj = 0; jj < 4; jj++)
            c[jj] = (a4v[jj] != 0.0f) ? ((acc[ii][jj] >= 0.1f) ? 1 : 2) : 0;
        *reinterpret_cast<uchar4*>(&code[(size_t)i * KN + jb]) = cc;
    }
}

// ---------------- MFMA bf16 GEMM body: 64x64 C tile, K=256 ----------------
// A f32 [M,K] row-major, B f32 [K,N] row-major, C f32. Per-block 256 thr = 4 waves;
// wave w computes rows [w*16, w*16+16) x 64 cols as 4 MFMA 16x16x32 per K-step.
template <bool TANH>
__device__ __forceinline__ void mfma_gemm_body(
    const float* __restrict__ A, int lda, int bm,
    const float* __restrict__ B, int ldb, int bn,
    const float* __restrict__ bias, int bcol,
    float* __restrict__ C, int ldc, int cn, char* smem)
{
    short* As = (short*)smem;            // [64][40] bf16 (row m, col k), stride 40
    short* Bs = (short*)(smem + 5120);   // [64][40] bf16 (row n, col k) transposed
    int t = threadIdx.x;
    int w = t >> 6, lane = t & 63;
    int m16 = lane & 15, kq = lane >> 4;
    floatx4 acc0 = {0,0,0,0}, acc1 = {0,0,0,0}, acc2 = {0,0,0,0}, acc3 = {0,0,0,0};
    int ar = t >> 2, acq = (t & 3) * 8;     // A stage: row 0..63, k-offset {0,8,16,24}
    int bnn = t & 63, bkg = (t >> 6) * 8;   // B stage: col n 0..63, k-group {0,8,16,24}
    for (int kt = 0; kt < KD; kt += 32) {
        const float* pa = &A[(size_t)(bm + ar) * lda + kt + acq];
        float4 a0 = *(const float4*)pa;
        float4 a1 = *(const float4*)(pa + 4);
        short8 av;
        av[0] = f2bs(a0.x); av[1] = f2bs(a0.y); av[2] = f2bs(a0.z); av[3] = f2bs(a0.w);
        av[4] = f2bs(a1.x); av[5] = f2bs(a1.y); av[6] = f2bs(a1.z); av[7] = f2bs(a1.w);
        const float* pb = &B[(size_t)(kt + bkg) * ldb + bn + bnn];
        short8 bv;
        #pragma unroll
        for (int u = 0; u < 8; u++) bv[u] = f2bs(pb[(size_t)u * ldb]);
        __syncthreads();   // previous iteration's frag reads complete
        *(short8*)&As[ar * 40 + acq] = av;
        *(short8*)&Bs[bnn * 40 + bkg] = bv;
        __syncthreads();
        short8 af  = *(short8*)&As[(w * 16 + m16) * 40 + kq * 8];
        short8 bf0 = *(short8*)&Bs[( 0 + m16) * 40 + kq * 8];
        short8 bf1 = *(short8*)&Bs[(16 + m16) * 40 + kq * 8];
        short8 bf2 = *(short8*)&Bs[(32 + m16) * 40 + kq * 8];
        short8 bf3 = *(short8*)&Bs[(48 + m16) * 40 + kq * 8];
        acc0 = __builtin_amdgcn_mfma_f32_16x16x32_bf16(af, bf0, acc0, 0, 0, 0);
        acc1 = __builtin_amdgcn_mfma_f32_16x16x32_bf16(af, bf1, acc1, 0, 0, 0);
        acc2 = __builtin_amdgcn_mfma_f32_16x16x32_bf16(af, bf2, acc2, 0, 0, 0);
        acc3 = __builtin_amdgcn_mfma_f32_16x16x32_bf16(af, bf3, acc3, 0, 0, 0);
    }
    // epilogue: C/D layout col=lane&15, row=(lane>>4)*4+reg
    int row0 = bm + w * 16 + kq * 4;
    floatx4 accs[4] = {acc0, acc1, acc2, acc3};
    #pragma unroll
    for (int nb = 0; nb < 4; nb++) {
        #pragma unroll
        for (int r = 0; r < 4; r++) {
            int col = nb * 16 + m16;
            float v = accs[nb][r] + bias[bcol + col];
            if (TANH) {
                float vc = fminf(fmaxf(v, -9.0f), 9.0f);
                float ex = __expf(2.0f * vc);
                v = (ex - 1.0f) / (ex + 1.0f);
            }
            C[(size_t)(row0 + r) * ldc + cn + col] = v;
        }
    }
}

// ---------------- K2: phase1 = corr_mask (1024 blks) + emb GEMM (640 blks) --
struct Ptr5 { float* c0; float* c1; float* c2; float* c3; float* c4; };
__global__ __launch_bounds__(256) void phase1_kernel(
    const float* __restrict__ ycs, const float* __restrict__ adj,
    unsigned char* __restrict__ code,
    const float* __restrict__ emb, const float* __restrict__ Wbig,
    const float* __restrict__ biasbig, Ptr5 cp)
{
    __shared__ alignas(16) char smem[10240];
    int blk = blockIdx.x;
    if (blk < 1024) {
        corr_body(ycs, adj, code, blk, smem);
    } else {
        int b = blk - 1024;            // 0..639
        int tn = b % 20, tm = b / 20;
        int bn = tn * 64;
        int buf = bn >> 8, coloff = bn & 255;
        float* C = (buf == 0) ? cp.c0 : (buf == 1) ? cp.c1 : (buf == 2) ? cp.c2
                 : (buf == 3) ? cp.c3 : cp.c4;
        mfma_gemm_body<false>(emb, KD, tm * 64, Wbig, 1280, bn, biasbig, bn, C, KD, coloff, smem);
    }
}

// K3b: [G_pos;G_neg](4096x256) @ {mlp_pos_w|mlp_neg_w} -> [psup;nsup]
__global__ __launch_bounds__(256) void gemm_mlp(const float* __restrict__ Astack,
                                                const float* __restrict__ B0,
                                                const float* __restrict__ B1,
                                                const float* __restrict__ b0,
                                                const float* __restrict__ b1,
                                                float* __restrict__ Cstack) {
    __shared__ alignas(16) char smem[10240];
    int bm = blockIdx.y * 64;
    bool sel = bm >= KN;
    mfma_gemm_body<false>(Astack, KD, bm, sel ? B1 : B0, KD, blockIdx.x * 64,
                          sel ? b1 : b0, blockIdx.x * 64, Cstack, KD, blockIdx.x * 64, smem);
}

// K3c: [sup;psup;nsup](6144x256) @ sem_w1 + b, tanh -> [T0;T1;T2]
__global__ __launch_bounds__(256) void gemm_sem(const float* __restrict__ Astack,
                                                const float* __restrict__ B,
                                                const float* __restrict__ bias,
                                                float* __restrict__ Cstack) {
    __shared__ alignas(16) char smem[10240];
    mfma_gemm_body<true>(Astack, KD, blockIdx.y * 64, B, KD, blockIdx.x * 64,
                         bias, blockIdx.x * 64, Cstack, KD, blockIdx.x * 64, smem);
}

// ---------------- K4: per-(n,h) attention scores f1,f2 (pos+neg fused) ----
__global__ __launch_bounds__(256) void f1f2_kernel(const float* __restrict__ Sp,
                                                   const float* __restrict__ Sn,
                                                   const float* __restrict__ wup,
                                                   const float* __restrict__ wvp,
                                                   const float* __restrict__ wun,
                                                   const float* __restrict__ wvn,
                                                   float* __restrict__ f1p,
                                                   float* __restrict__ f2p,
                                                   float* __restrict__ f1n,
                                                   float* __restrict__ f2n) {
    int b = blockIdx.x;
    int rel = b >> 11;               // 0 pos, 1 neg
    int n = b & (KN - 1);
    int h = threadIdx.x >> 6, lane = threadIdx.x & 63;
    const float* S = rel ? Sn : Sp;
    const float* wu = rel ? wun : wup;
    const float* wv = rel ? wvn : wvp;
    float* f1 = rel ? f1n : f1p;
    float* f2 = rel ? f2n : f2p;
    float v = S[(size_t)n * KD + h * KF + lane];
    float s1 = wave_sum(v * wu[h * KF + lane]);
    float s2 = wave_sum(v * wv[h * KF + lane]);
    if (lane == 0) { f1[h * KN + n] = s1; f2[h * KN + n] = s2; }
}

// ---------------- K5: sparse GAT row, block per (i,rel), wave = head ------
#define MAXE 256
__global__ __launch_bounds__(256) void attn_kernel(
    const unsigned char* __restrict__ code,
    const float* __restrict__ f1p, const float* __restrict__ f2p,
    const float* __restrict__ Sp, const float* __restrict__ Pp,
    const float* __restrict__ bp, float* __restrict__ Gp,
    const float* __restrict__ f1n, const float* __restrict__ f2n,
    const float* __restrict__ Sn, const float* __restrict__ Pn,
    const float* __restrict__ bn_, float* __restrict__ Gn)
{
    __shared__ int jl[MAXE];
    __shared__ float lg[KH][MAXE];
    __shared__ int cnt;
    int blk = blockIdx.x;
    int rel = blk >> 11;
    int i = blk & (KN - 1);
    unsigned char want = rel ? (unsigned char)2 : (unsigned char)1;
    const float* f1 = rel ? f1n : f1p;
    const float* f2 = rel ? f2n : f2p;
    const float* S  = rel ? Sn : Sp;
    const float* P  = rel ? Pn : Pp;
    const float* b  = rel ? bn_ : bp;
    float* G        = rel ? Gn : Gp;
    int w = threadIdx.x >> 6, lane = threadIdx.x & 63;
    if (threadIdx.x == 0) cnt = 0;
    __syncthreads();
    // cooperative scan: wave w covers columns [w*512, w*512+512)
    #pragma unroll
    for (int it = 0; it < 2; it++) {
        int base = w * 512 + it * 256;
        uchar4 cv = *reinterpret_cast<const uchar4*>(&code[(size_t)i * KN + base + lane * 4]);
        const unsigned char* ce = (const unsigned char*)&cv;
        #pragma unroll
        for (int e = 0; e < 4; e++) {
            bool p = (ce[e] == want);
            unsigned long long bal = __ballot(p);
            int tot = __popcll(bal);
            int basepos = 0;
            if (lane == 0 && tot) basepos = atomicAdd(&cnt, tot);
            basepos = __shfl(basepos, 0, 64);
            if (p) {
                int idx = basepos + __popcll(bal & ((1ull << lane) - 1ull));
                if (idx < MAXE) jl[idx] = base + lane * 4 + e;
            }
        }
    }
    __syncthreads();
    int count = cnt; if (count > MAXE) count = MAXE;
    int h = w;                                  // one wave per head
    float f2i = f2[h * KN + i];
    float m = -1e30f;
    for (int k = lane; k < count; k += 64) {
        int j = jl[k];
        float x = f1[h * KN + j] + f2i;
        x = (x > 0.0f) ? x : 0.2f * x;          // leaky_relu 0.2
        lg[h][k] = x;
        m = fmaxf(m, x);
    }
    m = wave_max(m);
    float ps = 0.0f;
    for (int k = lane; k < count; k += 64) {
        float e = __expf(lg[h][k] - m);
        lg[h][k] = e;
        ps += e;
    }
    float denom = wave_sum(ps);
    float acc = 0.0f;
    for (int k = 0; k < count; k++)
        acc += lg[h][k] * S[(size_t)jl[k] * KD + h * KF + lane];
    float outv = count ? acc * (1.0f / denom) : 0.0f;
    int col = h * KF + lane;
    G[(size_t)i * KD + col] = outv + b[col] + P[(size_t)i * KD + col];
}

// ---------------- K8: semantic attention blend + colsum partials --------
__global__ __launch_bounds__(256) void combine_kernel(const float* __restrict__ T0,
                                                      const float* __restrict__ T1,
                                                      const float* __restrict__ T2,
                                                      const float* __restrict__ w2,
                                                      const float* __restrict__ sup,
                                                      const float* __restrict__ psup,
                                                      const float* __restrict__ nsup,
                                                      float* __restrict__ X,
                                                      float* __restrict__ colsum) {
    int n = blockIdx.x, d = threadIdx.x;
    size_t idx = (size_t)n * KD + d;
    float w2d = w2[d];
    float p0 = T0[idx] * w2d, p1 = T1[idx] * w2d, p2 = T2[idx] * w2d;
    __shared__ float sbuf[4][3];
    int wv = d >> 6, lane = d & 63;
    float s0 = wave_sum(p0), s1 = wave_sum(p1), s2 = wave_sum(p2);
    if (lane == 0) { sbuf[wv][0] = s0; sbuf[wv][1] = s1; sbuf[wv][2] = s2; }
    __syncthreads();
    float w0 = sbuf[0][0] + sbuf[1][0] + sbuf[2][0] + sbuf[3][0];
    float w1 = sbuf[0][1] + sbuf[1][1] + sbuf[2][1] + sbuf[3][1];
    float w2l = sbuf[0][2] + sbuf[1][2] + sbuf[2][2] + sbuf[3][2];
    float mm = fmaxf(w0, fmaxf(w1, w2l));
    float e0 = __expf(w0 - mm), e1 = __expf(w1 - mm), e2 = __expf(w2l - mm);
    float inv = 1.0f / (e0 + e1 + e2);
    float x = (e0 * inv) * sup[idx] + (e1 * inv) * psup[idx] + (e2 * inv) * nsup[idx];
    X[idx] = x;
    atomicAdd(&colsum[(n & 7) * KD + d], x);
}

// ---------------- K9: PairNorm PN-SI + store ----------------
__global__ __launch_bounds__(256) void final_kernel(const float* __restrict__ X,
                                                    const float* __restrict__ colsum,
                                                    float* __restrict__ out) {
    int n = blockIdx.x, d = threadIdx.x;
    float cs = 0.0f;
    #pragma unroll
    for (int r = 0; r < 8; r++) cs += colsum[r * KD + d];
    float mean = cs * (1.0f / KN);
    float xc = X[(size_t)n * KD + d] - mean;
    __shared__ float sbuf[4];
    int wv = d >> 6, lane = d & 63;
    float s = wave_sum(xc * xc);
    if (lane == 0) sbuf[wv] = s;
    __syncthreads();
    float ss = sbuf[0] + sbuf[1] + sbuf[2] + sbuf[3];
    out[(size_t)n * KD + d] = xc * rsqrtf(1e-6f + ss);
}

// ---------------- host ----------------
extern "C" void kernel_launch(void* const* d_in, const int* in_sizes, int n_in,
                              void* d_out, int out_size, void* d_ws, size_t ws_size,
                              hipStream_t stream) {
    typedef const float* fp;
    fp emb    = (fp)d_in[0];
    fp y_as_x = (fp)d_in[1];
    fp adj    = (fp)d_in[2];
    fp pos_w  = (fp)d_in[3],  pos_wu = (fp)d_in[4],  pos_wv = (fp)d_in[5];
    fp pos_b  = (fp)d_in[6],  pos_pw = (fp)d_in[7],  pos_pb = (fp)d_in[8];
    fp neg_w  = (fp)d_in[9],  neg_wu = (fp)d_in[10], neg_wv = (fp)d_in[11];
    fp neg_b  = (fp)d_in[12], neg_pw = (fp)d_in[13], neg_pb = (fp)d_in[14];
    fp self_w = (fp)d_in[15], self_b = (fp)d_in[16];
    fp mlp_pos_w = (fp)d_in[17], mlp_pos_b = (fp)d_in[18];
    fp mlp_neg_w = (fp)d_in[19], mlp_neg_b = (fp)d_in[20];
    fp sem_w1 = (fp)d_in[21], sem_b1 = (fp)d_in[22], sem_w2 = (fp)d_in[23];
    float* out = (float*)d_out;

    char* ws = (char*)d_ws;
    float* ycs        = (float*)(ws + 0x0000000);          // 512 KB; aliased below after corr
    float* f1p        = (float*)(ws + 0x0000000);
    float* f2p        = (float*)(ws + 0x0008000);
    float* f1n        = (float*)(ws + 0x0010000);
    float* f2n        = (float*)(ws + 0x0018000);
    unsigned char* cd = (unsigned char*)(ws + 0x0080000);  // 4 MB
    float* S_pos      = (float*)(ws + 0x0480000);          // 2 MB each
    float* S_neg      = (float*)(ws + 0x0680000);
    float* P_pos      = (float*)(ws + 0x0880000);          // later T0
    float* P_neg      = (float*)(ws + 0x0A80000);          // later T1
    float* G_pos      = (float*)(ws + 0x0C80000);          // later T2 (G_pos|G_neg contiguous)
    float* G_neg      = (float*)(ws + 0x0E80000);          // later X
    float* sup        = (float*)(ws + 0x1080000);          // sup|psup|nsup contiguous
    float* psup       = (float*)(ws + 0x1280000);          // psup|nsup = mlp C stack
    float* nsup       = (float*)(ws + 0x1480000);          // hosts Wbig until mlp runs
    float* Wbig       = (float*)(ws + 0x1480000);          // 1.25 MB, dead before nsup written
    float* biasbig    = (float*)(ws + 0x15C0000);
    float* colsum     = (float*)(ws + 0x1680000);          // 8 KB, fresh region
    float* T0 = P_pos, *T1 = P_neg, *T2 = G_pos, *X = G_neg;

    setup_kernel<<<768, 256, 0, stream>>>(y_as_x, ycs, pos_w, neg_w, pos_pw, neg_pw,
                                          self_w, pos_pb, neg_pb, self_b,
                                          Wbig, biasbig, colsum);

    Ptr5 cp = {S_pos, S_neg, P_pos, P_neg, sup};
    phase1_kernel<<<1024 + 640, 256, 0, stream>>>(ycs, adj, cd, emb, Wbig, biasbig, cp);

    f1f2_kernel<<<2 * KN, 256, 0, stream>>>(S_pos, S_neg, pos_wu, pos_wv, neg_wu, neg_wv,
                                            f1p, f2p, f1n, f2n);

    attn_kernel<<<2 * KN, 256, 0, stream>>>(cd,
                                            f1p, f2p, S_pos, P_pos, pos_b, G_pos,
                                            f1n, f2n, S_neg, P_neg, neg_b, G_neg);

    gemm_mlp<<<dim3(4, 64), 256, 0, stream>>>(G_pos, mlp_pos_w, mlp_neg_w,
                                              mlp_pos_b, mlp_neg_b, psup);
    gemm_sem<<<dim3(4, 96), 256, 0, stream>>>(sup, sem_w1, sem_b1, T0);

    combine_kernel<<<KN, 256, 0, stream>>>(T0, T1, T2, sem_w2, sup, psup, nsup, X, colsum);
    final_kernel<<<KN, 256, 0, stream>>>(X, colsum, out);
}